// Round 13
// baseline (692.636 us; speedup 1.0000x reference)
//
#include <hip/hip_runtime.h>
#include <math.h>

// ---------------------------------------------------------------------------
// Round 22: raise TLP — 12 waves/block (768 thr), 3 waves/SIMD. r20/r21
// post-mortem: LDS-path and VGPR-path tie at ~345us; per-step stall is
// ~1100cyc/part at each vmcnt with only 2 waves/SIMD to cover it (Occupancy
// 22.5%); VGPR capped at 128 defeated deep per-wave pipelines twice. Fix:
// each wave owns 2 unit-groups (8 frags/kk, acc[2][8]=64 VGPR) -> wave
// state ~159 VGPR fits the 170 budget of 3 waves/EU (waves_per_eu(3,3)).
// frag = ug*4+g is linear in unit-groups -> wave w owns frags [8w,8w+8),
// pack kernels unchanged, per-CU weight traffic unchanged. kk loop keeps
// the proven counted-vmcnt schedule (issue c+2, vmcnt(8), 8 MFMAs) as
// 3-kk macro-iterations (buffer rotation period 3 -> all static) + 2-kk
// tail (waits 8/8/4/0). Telltales: VGPR 155-170, Occupancy ~34%.
// ---------------------------------------------------------------------------

using bf16x8 = __attribute__((ext_vector_type(8))) short;
using f32x4  = __attribute__((ext_vector_type(4))) float;

enum { EPI_NONE = 0, EPI_RELU = 1, EPI_TANH = 2 };

__device__ inline unsigned short f2bf(float f) {
    union { float f; unsigned u; } v; v.f = f;
    unsigned r = v.u + 0x7FFFu + ((v.u >> 16) & 1u);
    return (unsigned short)(r >> 16);
}
__device__ inline float sigf(float x) {
    return __fdividef(1.f, 1.f + __expf(-x));
}
__device__ inline float tanhfast(float x) {
    return 1.f - __fdividef(2.f, 1.f + __expf(2.f * x));
}

__device__ inline void gll16(const void* g, void* l) {
    __builtin_amdgcn_global_load_lds(
        (const __attribute__((address_space(1))) unsigned int*)(uintptr_t)g,
        (__attribute__((address_space(3))) unsigned int*)(unsigned int)(uintptr_t)l,
        16, 0, 0);
}

// ---------------------------------------------------------------------------
// Persistent LSTM: grid 256 x 768 threads (12 waves), 3 waves/SIMD.
// Block b owns batch rows [32b, 32b+32). Ab [32][456] bf16 holds x|h.
// Wave w (0..11) owns unit-groups ug in {2w, 2w+1} = packed fragments
// [8w, 8w+8) per kk; all 32 rows (mi 0..1).
// Weight layout (pack_lstm2, unchanged): elem(frag, k=kk*32+quad*8+j) at
// kk*49152 + frag*512 + (quad*16+lm)*8 + j, frag = ug*4 + gate.
// ---------------------------------------------------------------------------
#define PROWS 32
#define PLDA  456

// load the 4 fragments of chunk (kkv, partv) directly into registers
#define LOADB_G(dst, kkv, partv)                                               \
    _Pragma("unroll")                                                          \
    for (int q = 0; q < 4; ++q)                                                \
        dst[q] = *(const bf16x8*)(Wt + (size_t)(kkv) * 49152                   \
                                  + (w * 8 + (partv) * 4 + q) * 512            \
                                  + lane * 8);

// load the 2 A-fragments for K-slice kkv from Ab
#define LOADA(dst, kkv)                                                        \
    _Pragma("unroll")                                                          \
    for (int mi = 0; mi < 2; ++mi)                                             \
        dst[mi] = *(const bf16x8*)&Ab[(mi * 16 + lm) * PLDA + (kkv) * 32       \
                                      + quad * 8];

// 8 MFMAs for part partv (LITERAL 0/1 -> static acc indices)
#define MFMA8(partv, bRv)                                                      \
    _Pragma("unroll")                                                          \
    for (int q = 0; q < 4; ++q) {                                              \
        acc[0][(partv) * 4 + q] = __builtin_amdgcn_mfma_f32_16x16x32_bf16(     \
            aF[0], bRv[q], acc[0][(partv) * 4 + q], 0, 0, 0);                  \
        acc[1][(partv) * 4 + q] = __builtin_amdgcn_mfma_f32_16x16x32_bf16(     \
            aF[1], bRv[q], acc[1][(partv) * 4 + q], 0, 0, 0);                  \
    }

#define VMWAIT(n)                                                              \
    asm volatile("s_waitcnt vmcnt(" #n ")" ::: "memory");                      \
    __builtin_amdgcn_sched_barrier(0);

__global__ __attribute__((amdgpu_flat_work_group_size(768, 768),
                          amdgpu_waves_per_eu(3, 3)))
void lstm_persist(const float* __restrict__ x,
                  const float* __restrict__ m,
                  const unsigned short* __restrict__ WtE,
                  const unsigned short* __restrict__ WtD,
                  const float* __restrict__ bIE,
                  const float* __restrict__ bID,
                  unsigned short* __restrict__ dcd)
{
    __shared__ __attribute__((aligned(16))) unsigned short Ab[PROWS * PLDA];
    const int tid  = threadIdx.x;
    const int lane = tid & 63;
    const int w    = tid >> 6;           // 0..11
    const int lm   = lane & 15, quad = lane >> 4;
    const int brow = blockIdx.x * PROWS;
    const int kk0  = blockIdx.x % 14;    // per-block kk stagger (L2 spread)

    // zero A-buffer (pads stay 0 forever), then stage x slice t=0
    for (int i = tid; i < PROWS * PLDA; i += 768) Ab[i] = 0;
    __syncthreads();
    for (int i = tid; i < PROWS * 69; i += 768) {
        const int r = i / 69, f = i - r * 69;
        Ab[r * PLDA + f] = f2bf(x[((size_t)(brow + r) * 7 + 0) * 69 + f]);
    }

    float creg[2][2][4] = {};   // cell state: [mi][uu][r], unit (2w+uu)*16+lm
    float bI[2][4];             // bias: [uu][gate]

    for (int s = 0; s < 14; ++s) {
        const bool enc = (s < 7);
        const int t = enc ? s : s - 7;
        const unsigned short* Wt = enc ? WtE : WtD;

        if (s == 0 || s == 7) {
            const float* bsrc = enc ? bIE : bID;
            #pragma unroll
            for (int uu = 0; uu < 2; ++uu)
                #pragma unroll
                for (int g = 0; g < 4; ++g)
                    bI[uu][g] = bsrc[(2 * w + uu) * 64 + g * 16 + lm];
        }

        __syncthreads();   // Ab (x for s, h from s-1) visible; vmcnt drained

        f32x4 acc[2][8] = {};
        {
            bf16x8 b0[4], b1[4], b2[4];
            // prologue: both chunks of kk0 (8 loads outstanding)
            LOADB_G(b0, kk0, 0)
            LOADB_G(b1, kk0, 1)
            int ka = kk0;
            // main: 4 macro-iterations x 3 kk (buffer rotation period 3)
            #pragma unroll 1
            for (int it = 0; it < 4; ++it) {
                const int kb = (ka == 13) ? 0 : ka + 1;
                const int kc = (kb == 13) ? 0 : kb + 1;
                const int kd = (kc == 13) ? 0 : kc + 1;
                bf16x8 aF[2];
                LOADB_G(b2, kb, 0)
                VMWAIT(8)
                LOADA(aF, ka)
                MFMA8(0, b0)
                LOADB_G(b0, kb, 1)
                VMWAIT(8)
                MFMA8(1, b1)
                LOADB_G(b1, kc, 0)
                VMWAIT(8)
                LOADA(aF, kb)
                MFMA8(0, b2)
                LOADB_G(b2, kc, 1)
                VMWAIT(8)
                MFMA8(1, b0)
                LOADB_G(b0, kd, 0)
                VMWAIT(8)
                LOADA(aF, kc)
                MFMA8(0, b1)
                LOADB_G(b1, kd, 1)
                VMWAIT(8)
                MFMA8(1, b2)
                ka = kd;
            }
            // tail: 2 kk (ka = kk0+12, kb = kk0+13 mod 14)
            {
                const int kb = (ka == 13) ? 0 : ka + 1;
                bf16x8 aF[2];
                LOADB_G(b2, kb, 0)
                VMWAIT(8)
                LOADA(aF, ka)
                MFMA8(0, b0)
                LOADB_G(b0, kb, 1)
                VMWAIT(8)
                MFMA8(1, b1)
                VMWAIT(4)
                LOADA(aF, kb)
                MFMA8(0, b2)
                VMWAIT(0)
                MFMA8(1, b0)
            }
        }

        __syncthreads();   // all Ab reads done before h overwrite

        // epilogue: gates -> c (regs) -> h -> Ab[hoff+u] (+ dcd in dec phase)
        const int hoff = (s < 6) ? 69 : 45;   // layout of step s+1
        #pragma unroll
        for (int mi = 0; mi < 2; ++mi)
            #pragma unroll
            for (int uu = 0; uu < 2; ++uu) {
                const int u = (2 * w + uu) * 16 + lm;
                const bool uok = (u < 356);
                #pragma unroll
                for (int r = 0; r < 4; ++r) {
                    const float zi = acc[mi][uu * 4 + 0][r] + bI[uu][0];
                    const float zf = acc[mi][uu * 4 + 1][r] + bI[uu][1];
                    const float zg = acc[mi][uu * 4 + 2][r] + bI[uu][2];
                    const float zo = acc[mi][uu * 4 + 3][r] + bI[uu][3];
                    const float cn = sigf(zf) * creg[mi][uu][r]
                                   + sigf(zi) * tanhfast(zg);
                    creg[mi][uu][r] = cn;
                    const unsigned short hb = f2bf(sigf(zo) * tanhfast(cn));
                    const int rl = mi * 16 + quad * 4 + r;
                    if (uok) {
                        if (s < 13) Ab[rl * PLDA + hoff + u] = hb;
                        if (!enc)
                            dcd[(size_t)(brow + rl) * 2496 + t * 356 + u] = hb;
                    }
                }
            }

        // stage x/m slice for step s+1 (disjoint from h region)
        const int sn = s + 1;
        if (sn < 7) {
            for (int i = tid; i < PROWS * 69; i += 768) {
                const int r = i / 69, f = i - r * 69;
                Ab[r * PLDA + f] =
                    f2bf(x[((size_t)(brow + r) * 7 + sn) * 69 + f]);
            }
        } else if (sn < 14) {
            for (int i = tid; i < PROWS * 45; i += 768) {
                const int r = i / 45, f = i - r * 45;
                Ab[r * PLDA + f] =
                    f2bf(m[((size_t)(brow + r) * 7 + (sn - 7)) * 45 + f]);
            }
        }
    }
}

// ---- MLP GEMM machinery (unchanged, proven) ----

#define STAGE(A_, Bt_, K_, k0_, b_)                                            \
    {                                                                          \
        const int row = tid >> 2, kc = tid & 3;                                \
        gll16((A_)  + (size_t)(m0 + row) * (K_) + (k0_) + kc * 8,              \
              (void*)&As[b_][tid * 8]);                                        \
        gll16((Bt_) + (size_t)(n0 + row) * (K_) + (k0_) + kc * 8,              \
              (void*)&Bs[b_][tid * 8]);                                        \
    }

#define GEMM_CORE(A_, Bt_, K_)                                                 \
    STAGE(A_, Bt_, K_, 0, 0)                                                   \
    {                                                                          \
        const int niter = (K_) / 32;                                           \
        for (int it = 0; it < niter; ++it) {                                   \
            __syncthreads();                                                   \
            if (it + 1 < niter) {                                              \
                const int kn = (it + 1) * 32, bn = (it + 1) & 1;               \
                STAGE(A_, Bt_, K_, kn, bn)                                     \
            }                                                                  \
            const unsigned short* Asb = As[it & 1];                            \
            const unsigned short* Bsb = Bs[it & 1];                            \
            bf16x8 aF[2], bF[4];                                               \
            _Pragma("unroll")                                                  \
            for (int mi = 0; mi < 2; ++mi)                                     \
                aF[mi] = *(const bf16x8*)(Asb + (wr*32 + mi*16 + lm)*32 + quad*8);\
            _Pragma("unroll")                                                  \
            for (int ni = 0; ni < 4; ++ni)                                     \
                bF[ni] = *(const bf16x8*)(Bsb + (wc*64 + ni*16 + lm)*32 + quad*8);\
            _Pragma("unroll")                                                  \
            for (int mi = 0; mi < 2; ++mi)                                     \
                _Pragma("unroll")                                              \
                for (int ni = 0; ni < 4; ++ni)                                 \
                    acc[mi][ni] = __builtin_amdgcn_mfma_f32_16x16x32_bf16(     \
                        aF[mi], bF[ni], acc[mi][ni], 0, 0, 0);                 \
        }                                                                      \
    }

#define GEMM_PREAMBLE                                                          \
    __shared__ __attribute__((aligned(16))) unsigned short As[2][128 * 32];    \
    __shared__ __attribute__((aligned(16))) unsigned short Bs[2][128 * 32];    \
    const int tid  = threadIdx.x;                                              \
    const int lane = tid & 63;                                                 \
    const int w    = tid >> 6;          /* 0..7 */                             \
    const int wr   = w >> 1, wc = w & 1; /* 4x2 wave grid */                   \
    const int lm   = lane & 15, quad = lane >> 4;                              \
    const int m0   = blockIdx.x * 128, n0 = blockIdx.y * 128;                  \
    f32x4 acc[2][4] = {};

template <int EPI, int OUT_BF16, int NGUARD>
__global__ __launch_bounds__(512, 6)
void gemm_mfma(const unsigned short* __restrict__ A,
               const unsigned short* __restrict__ Bt,
               const float* __restrict__ bias,
               void* __restrict__ Cv, int ldc, int Nreal, int K)
{
    GEMM_PREAMBLE
    GEMM_CORE(A, Bt, K)
    #pragma unroll
    for (int mi = 0; mi < 2; ++mi)
        #pragma unroll
        for (int r = 0; r < 4; ++r) {
            const size_t row = m0 + wr * 32 + mi * 16 + quad * 4 + r;
            #pragma unroll
            for (int ni = 0; ni < 4; ++ni) {
                const int col = n0 + wc * 64 + ni * 16 + lm;
                if (!NGUARD || col < Nreal) {
                    float v = acc[mi][ni][r] + bias[col];
                    if (EPI == EPI_RELU) v = fmaxf(v, 0.f);
                    if (EPI == EPI_TANH) v = tanhfast(v);
                    if (OUT_BF16) ((unsigned short*)Cv)[row * ldc + col] = f2bf(v);
                    else          ((float*)Cv)[row * ldc + col] = v;
                }
            }
        }
}

// ---- LSTM weight pack (enc+dec in one launch; blockIdx.y selects) ----
// kk-major, lane-major fragment layout (UNCHANGED from r19):
//   elem(np, k) -> kk*49152 + frag*512 + (quad*16+lm)*8 + j   (shorts)
// where frag = (np>>4) reinterpreted as ug*4+g, np = frag*16 + lm,
// k = kk*32+quad*8+j. Kp=448 both (dec k>=401 zero-padded).
struct PackArgs {
    const float *Wa0, *Wb0, *bias0; unsigned short* Wt0; float* bI0; int K10, K0, Kp0;
    const float *Wa1, *Wb1, *bias1; unsigned short* Wt1; float* bI1; int K11, K1, Kp1;
};
__global__ void pack_lstm2(PackArgs p)
{
    const float* Wa  = blockIdx.y ? p.Wa1  : p.Wa0;
    const float* Wb  = blockIdx.y ? p.Wb1  : p.Wb0;
    const float* bias= blockIdx.y ? p.bias1: p.bias0;
    unsigned short* Wt = blockIdx.y ? p.Wt1 : p.Wt0;
    float* biasI = blockIdx.y ? p.bI1 : p.bI0;
    const int K1 = blockIdx.y ? p.K11 : p.K10;
    const int K  = blockIdx.y ? p.K1  : p.K0;
    const int Kp = blockIdx.y ? p.Kp1 : p.Kp0;
    const int idx = blockIdx.x * 256 + threadIdx.x;
    if (idx >= 1536 * Kp) return;
    const int np = idx / Kp, k = idx - np * Kp;
    const int ub = np >> 6, g = (np >> 4) & 3, ul = np & 15;
    const int u = ub * 16 + ul;
    const bool valid = (u < 356);
    const int norig = g * 356 + u;
    float v = 0.f;
    if (valid && k < K)
        v = (k < K1) ? Wa[(size_t)k * 1424 + norig]
                     : Wb[(size_t)(k - K1) * 1424 + norig];
    // kk-major, lane-major fragment layout
    const int wv = np / 192, rem = np - wv * 192;
    const int ni = rem >> 4, lmv = rem & 15;
    const int kkv = k >> 5, kq = k & 31;
    const int qd = kq >> 3, j = kq & 7;
    Wt[(size_t)kkv * 49152 + (size_t)(wv * 12 + ni) * 512 + (qd * 16 + lmv) * 8 + j]
        = f2bf(v);
    if (k == 0) biasI[np] = valid ? bias[norig] : 0.f;
}

// ---- MLP weight transpose+pack (fp32 [K][N] -> bf16 [Np][Kp]) ----
__global__ void transpose_pack(const float* __restrict__ W, int K, int N,
                               unsigned short* __restrict__ Wt, int Kp, int Np)
{
    __shared__ float t[32][33];
    const int n0 = blockIdx.x * 32, k0 = blockIdx.y * 32;
    const int tx = threadIdx.x, ty = threadIdx.y;
    #pragma unroll
    for (int r = 0; r < 4; ++r) {
        const int k = k0 + ty + 8 * r, n = n0 + tx;
        t[ty + 8 * r][tx] = (k < K && n < N) ? W[(size_t)k * N + n] : 0.f;
    }
    __syncthreads();
    #pragma unroll
    for (int r = 0; r < 4; ++r) {
        const int k = k0 + tx, n = n0 + ty + 8 * r;
        if (k < Kp && n < Np) Wt[(size_t)n * Kp + k] = f2bf(t[tx][ty + 8 * r]);
    }
}

// three 1024x1024 transposes in one launch (blockIdx.z selects)
struct WP3 { const float *s0, *s1, *s2; unsigned short *d0, *d1, *d2; };
__global__ void transpose_pack3(WP3 p)
{
    __shared__ float t[32][33];
    const float* W = (blockIdx.z == 0) ? p.s0 : (blockIdx.z == 1) ? p.s1 : p.s2;
    unsigned short* Wt = (blockIdx.z == 0) ? p.d0 : (blockIdx.z == 1) ? p.d1 : p.d2;
    const int n0 = blockIdx.x * 32, k0 = blockIdx.y * 32;
    const int tx = threadIdx.x, ty = threadIdx.y;
    #pragma unroll
    for (int r = 0; r < 4; ++r)
        t[ty + 8 * r][tx] = W[(size_t)(k0 + ty + 8 * r) * 1024 + n0 + tx];
    __syncthreads();
    #pragma unroll
    for (int r = 0; r < 4; ++r)
        Wt[(size_t)(n0 + ty + 8 * r) * 1024 + k0 + tx] = f2bf(t[tx][ty + 8 * r]);
}

// ---- zero dcd pad cols (2492..2495 of each row) ----
__global__ void zero_dcd_pad(unsigned short* __restrict__ dcd)
{
    const int i = blockIdx.x * 256 + threadIdx.x;
    if (i < 8192 * 4) dcd[(size_t)(i >> 2) * 2496 + 2492 + (i & 3)] = 0;
}

extern "C" void kernel_launch(void* const* d_in, const int* in_sizes, int n_in,
                              void* d_out, int out_size, void* d_ws, size_t ws_size,
                              hipStream_t stream)
{
    const float* x     = (const float*)d_in[0];
    const float* m     = (const float*)d_in[1];
    const float* enc_W = (const float*)d_in[2];
    const float* enc_U = (const float*)d_in[3];
    const float* enc_b = (const float*)d_in[4];
    const float* dec_W = (const float*)d_in[5];
    const float* dec_Um= (const float*)d_in[6];
    const float* dec_b = (const float*)d_in[7];
    const float* W_map = (const float*)d_in[8];
    const float* b_map = (const float*)d_in[9];
    const float* W1    = (const float*)d_in[10];
    const float* b1    = (const float*)d_in[11];
    const float* W2    = (const float*)d_in[12];
    const float* b2    = (const float*)d_in[13];
    const float* W3    = (const float*)d_in[14];
    const float* b3    = (const float*)d_in[15];
    const float* W_out = (const float*)d_in[16];
    const float* b_out = (const float*)d_in[17];
    float* out = (float*)d_out;

    const int B = 8192, FE = 69, FD = 45;
    const int KMP = 2496;

    char* ws = (char*)d_ws;
    size_t off = 0;
    auto alloc = [&](size_t bytes) -> void* {
        void* p = ws + off; off = (off + bytes + 255) & ~(size_t)255; return p;
    };
    unsigned short* WtE = (unsigned short*)alloc((size_t)1536 * 448 * 2);
    unsigned short* WtD = (unsigned short*)alloc((size_t)1536 * 448 * 2);
    unsigned short* WtM = (unsigned short*)alloc((size_t)1024 * KMP * 2);
    unsigned short* Wt1 = (unsigned short*)alloc((size_t)1024 * 1024 * 2);
    unsigned short* Wt2 = (unsigned short*)alloc((size_t)1024 * 1024 * 2);
    unsigned short* Wt3 = (unsigned short*)alloc((size_t)1024 * 1024 * 2);
    unsigned short* WtO = (unsigned short*)alloc((size_t)256 * 1024 * 2);
    float* bIE = (float*)alloc(1536 * 4);
    float* bID = (float*)alloc(1536 * 4);
    unsigned short* dcd = (unsigned short*)alloc((size_t)B * KMP * 2);
    unsigned short* a1  = (unsigned short*)alloc((size_t)B * 1024 * 2);
    unsigned short* a2  = (unsigned short*)alloc((size_t)B * 1024 * 2);

    // ---- weight packing (Kp=448 both, kk-major lane-major frags) ----
    PackArgs pa{enc_W, enc_U, enc_b, WtE, bIE, FE, FE + 356, 448,
                dec_W, dec_Um, dec_b, WtD, bID, FD, FD + 356, 448};
    pack_lstm2<<<dim3((1536 * 448 + 255) / 256, 2), 256, 0, stream>>>(pa);
    const dim3 tb(32, 8);
    transpose_pack<<<dim3(1024 / 32, KMP / 32), tb, 0, stream>>>(
        W_map, 2492, 1024, WtM, KMP, 1024);
    WP3 p3{W1, W2, W3, Wt1, Wt2, Wt3};
    transpose_pack3<<<dim3(32, 32, 3), tb, 0, stream>>>(p3);
    transpose_pack<<<dim3(256 / 32, 1024 / 32), tb, 0, stream>>>(
        W_out, 1024, 168, WtO, 1024, 256);
    zero_dcd_pad<<<(8192 * 4 + 255) / 256, 256, 0, stream>>>(dcd);

    // ---- persistent LSTM: one plain launch, zero grid sync ----
    lstm_persist<<<256, 768, 0, stream>>>(x, m, WtE, WtD, bIE, bID, dcd);

    // ---- MLP head ----
    gemm_mfma<EPI_RELU, 1, 0><<<dim3(64, 8), 512, 0, stream>>>(
        dcd, WtM, b_map, a1, 1024, 1024, KMP);
    gemm_mfma<EPI_TANH, 1, 0><<<dim3(64, 8), 512, 0, stream>>>(
        a1, Wt1, b1, a2, 1024, 1024, 1024);
    gemm_mfma<EPI_TANH, 1, 0><<<dim3(64, 8), 512, 0, stream>>>(
        a2, Wt2, b2, a1, 1024, 1024, 1024);
    gemm_mfma<EPI_TANH, 1, 0><<<dim3(64, 8), 512, 0, stream>>>(
        a1, Wt3, b3, a2, 1024, 1024, 1024);
    gemm_mfma<EPI_NONE, 0, 1><<<dim3(64, 2), 512, 0, stream>>>(
        a2, WtO, b_out, out, 168, 168, 1024);
}

// Round 14
// 554.800 us; speedup vs baseline: 1.2484x; 1.2484x over previous
//
#include <hip/hip_runtime.h>
#include <math.h>

// ---------------------------------------------------------------------------
// Round 23: 3 waves/SIMD with LDS-pinned occupancy. r22 post-mortem: chain
// 452us REGRESSION; VGPR=84 + FETCH/WRITE ~700MB = scratch spill. Cause:
// dropping Bs shrank LDS to 29KB -> 2 blocks/CU by LDS -> 6 waves/SIMD ->
// 85-VGPR budget -> register B-buffers spilled (waves_per_eu max ignored).
// Lesson: occupancy is reliably pinned ONLY by LDS footprint. Fix: 12-wave
// partition (acc[2][8]=64 VGPR) + r20's LDS-staged B (staging = 0 VGPR) +
// counted vmcnt. Per wave 2 private 4KB buffers (part0/part1), 1 chunk
// lookahead; Bs=96KB + Ab=29KB = 125.5KB -> exactly 1 block/CU -> 12 waves
// = 3/SIMD -> 170-VGPR budget, ~125 needed, no spill. Per kk: vmcnt(4),
// ds_read 4 frags, 8 MFMAs, re-stage same buf for kk+1 (reads retired
// before MFMAs issue -> overwrite safe). Never drains vmcnt in-loop.
// ---------------------------------------------------------------------------

using bf16x8 = __attribute__((ext_vector_type(8))) short;
using f32x4  = __attribute__((ext_vector_type(4))) float;

enum { EPI_NONE = 0, EPI_RELU = 1, EPI_TANH = 2 };

__device__ inline unsigned short f2bf(float f) {
    union { float f; unsigned u; } v; v.f = f;
    unsigned r = v.u + 0x7FFFu + ((v.u >> 16) & 1u);
    return (unsigned short)(r >> 16);
}
__device__ inline float sigf(float x) {
    return __fdividef(1.f, 1.f + __expf(-x));
}
__device__ inline float tanhfast(float x) {
    return 1.f - __fdividef(2.f, 1.f + __expf(2.f * x));
}

__device__ inline void gll16(const void* g, void* l) {
    __builtin_amdgcn_global_load_lds(
        (const __attribute__((address_space(1))) unsigned int*)(uintptr_t)g,
        (__attribute__((address_space(3))) unsigned int*)(unsigned int)(uintptr_t)l,
        16, 0, 0);
}

// ---------------------------------------------------------------------------
// Persistent LSTM: grid 256 x 768 threads (12 waves), 3 waves/SIMD
// (pinned by the 125.5KB LDS footprint -> 1 block/CU).
// Block b owns batch rows [32b, 32b+32). Ab [32][456] bf16 holds x|h.
// Wave w (0..11) owns packed fragments [8w, 8w+8) per kk = unit-groups
// {2w, 2w+1}; all 32 rows.
// Weight layout (pack_lstm2, kk-major lane-major): elem(frag, k=kk*32+
// quad*8+j) at kk*49152 + frag*512 + (quad*16+lm)*8 + j.
// Bs: per-wave 2 private buffers of 4 frags (4KB):
//   Bs[((w*2+buf)*4+q)*512 + lane*8]  (gll16 dest; ds_read lane*16B).
// ---------------------------------------------------------------------------
#define PROWS 32
#define PLDA  456

// stage chunk (kkv, partv) -> per-wave buffer bufv (4 x gll16, 4KB)
#define STAGE_CHUNK(bufv, kkv, partv)                                          \
    _Pragma("unroll")                                                          \
    for (int q = 0; q < 4; ++q)                                                \
        gll16(Wt + (size_t)(kkv) * 49152 + (w * 8 + (partv) * 4 + q) * 512     \
                  + lane * 8,                                                  \
              (void*)&Bs[((w * 2 + (bufv)) * 4 + q) * 512 + lane * 8]);

// read the 4 fragments of per-wave buffer bufv (conflict-free lane*16B)
#define LOADB4(dst, bufv)                                                      \
    _Pragma("unroll")                                                          \
    for (int q = 0; q < 4; ++q)                                                \
        dst[q] = *(const bf16x8*)&Bs[((w * 2 + (bufv)) * 4 + q) * 512          \
                                     + lane * 8];

// load the 2 A-fragments for K-slice kkv from Ab
#define LOADA(dst, kkv)                                                        \
    _Pragma("unroll")                                                          \
    for (int mi = 0; mi < 2; ++mi)                                             \
        dst[mi] = *(const bf16x8*)&Ab[(mi * 16 + lm) * PLDA + (kkv) * 32       \
                                      + quad * 8];

// 8 MFMAs for part partv (LITERAL 0/1 -> static acc indices)
#define MFMA8(partv, bRv)                                                      \
    _Pragma("unroll")                                                          \
    for (int q = 0; q < 4; ++q) {                                              \
        acc[0][(partv) * 4 + q] = __builtin_amdgcn_mfma_f32_16x16x32_bf16(     \
            aF[0], bRv[q], acc[0][(partv) * 4 + q], 0, 0, 0);                  \
        acc[1][(partv) * 4 + q] = __builtin_amdgcn_mfma_f32_16x16x32_bf16(     \
            aF[1], bRv[q], acc[1][(partv) * 4 + q], 0, 0, 0);                  \
    }

#define VMWAIT(n)                                                              \
    asm volatile("s_waitcnt vmcnt(" #n ")" ::: "memory");                      \
    __builtin_amdgcn_sched_barrier(0);

__global__ __attribute__((amdgpu_flat_work_group_size(768, 768)))
void lstm_persist(const float* __restrict__ x,
                  const float* __restrict__ m,
                  const unsigned short* __restrict__ WtE,
                  const unsigned short* __restrict__ WtD,
                  const float* __restrict__ bIE,
                  const float* __restrict__ bID,
                  unsigned short* __restrict__ dcd)
{
    __shared__ __attribute__((aligned(16))) unsigned short Ab[PROWS * PLDA];
    __shared__ __attribute__((aligned(16))) unsigned short Bs[49152];
    const int tid  = threadIdx.x;
    const int lane = tid & 63;
    const int w    = tid >> 6;           // 0..11
    const int lm   = lane & 15, quad = lane >> 4;
    const int brow = blockIdx.x * PROWS;
    const int kk0  = blockIdx.x % 14;    // per-block kk stagger (L2 spread)

    // zero A-buffer (pads stay 0 forever), then stage x slice t=0
    for (int i = tid; i < PROWS * PLDA; i += 768) Ab[i] = 0;
    __syncthreads();
    for (int i = tid; i < PROWS * 69; i += 768) {
        const int r = i / 69, f = i - r * 69;
        Ab[r * PLDA + f] = f2bf(x[((size_t)(brow + r) * 7 + 0) * 69 + f]);
    }

    float creg[2][2][4] = {};   // cell state: [mi][uu][r], unit (2w+uu)*16+lm
    float bI[2][4];             // bias: [uu][gate]

    for (int s = 0; s < 14; ++s) {
        const bool enc = (s < 7);
        const int t = enc ? s : s - 7;
        const unsigned short* Wt = enc ? WtE : WtD;

        if (s == 0 || s == 7) {
            const float* bsrc = enc ? bIE : bID;
            #pragma unroll
            for (int uu = 0; uu < 2; ++uu)
                #pragma unroll
                for (int g = 0; g < 4; ++g)
                    bI[uu][g] = bsrc[(2 * w + uu) * 64 + g * 16 + lm];
        }

        __syncthreads();   // Ab (x for s, h from s-1) visible; vmcnt drained

        f32x4 acc[2][8] = {};
        {
            // prologue: both parts of kk0 (8 loads outstanding)
            STAGE_CHUNK(0, kk0, 0)
            STAGE_CHUNK(1, kk0, 1)
            int kkc = kk0;
            #pragma unroll 1
            for (int i = 0; i < 14; ++i) {
                const int kkn = (kkc == 13) ? 0 : kkc + 1;
                bf16x8 aF[2], bR[4];
                // part 0: wait chunk(i,0); compute buf0; re-stage buf0
                VMWAIT(4)
                LOADA(aF, kkc)
                LOADB4(bR, 0)
                MFMA8(0, bR)          // lgkm auto-waited before first MFMA
                if (i < 13) STAGE_CHUNK(0, kkn, 0)
                // part 1: wait chunk(i,1); compute buf1; re-stage buf1
                if (i < 13) {
                    VMWAIT(4)
                } else {
                    VMWAIT(0)
                }
                LOADB4(bR, 1)
                MFMA8(1, bR)
                if (i < 13) STAGE_CHUNK(1, kkn, 1)
                kkc = kkn;
            }
        }

        __syncthreads();   // all Ab reads done before h overwrite

        // epilogue: gates -> c (regs) -> h -> Ab[hoff+u] (+ dcd in dec phase)
        const int hoff = (s < 6) ? 69 : 45;   // layout of step s+1
        #pragma unroll
        for (int mi = 0; mi < 2; ++mi)
            #pragma unroll
            for (int uu = 0; uu < 2; ++uu) {
                const int u = (2 * w + uu) * 16 + lm;
                const bool uok = (u < 356);
                #pragma unroll
                for (int r = 0; r < 4; ++r) {
                    const float zi = acc[mi][uu * 4 + 0][r] + bI[uu][0];
                    const float zf = acc[mi][uu * 4 + 1][r] + bI[uu][1];
                    const float zg = acc[mi][uu * 4 + 2][r] + bI[uu][2];
                    const float zo = acc[mi][uu * 4 + 3][r] + bI[uu][3];
                    const float cn = sigf(zf) * creg[mi][uu][r]
                                   + sigf(zi) * tanhfast(zg);
                    creg[mi][uu][r] = cn;
                    const unsigned short hb = f2bf(sigf(zo) * tanhfast(cn));
                    const int rl = mi * 16 + quad * 4 + r;
                    if (uok) {
                        if (s < 13) Ab[rl * PLDA + hoff + u] = hb;
                        if (!enc)
                            dcd[(size_t)(brow + rl) * 2496 + t * 356 + u] = hb;
                    }
                }
            }

        // stage x/m slice for step s+1 (disjoint from h region)
        const int sn = s + 1;
        if (sn < 7) {
            for (int i = tid; i < PROWS * 69; i += 768) {
                const int r = i / 69, f = i - r * 69;
                Ab[r * PLDA + f] =
                    f2bf(x[((size_t)(brow + r) * 7 + sn) * 69 + f]);
            }
        } else if (sn < 14) {
            for (int i = tid; i < PROWS * 45; i += 768) {
                const int r = i / 45, f = i - r * 45;
                Ab[r * PLDA + f] =
                    f2bf(m[((size_t)(brow + r) * 7 + (sn - 7)) * 45 + f]);
            }
        }
    }
}

// ---- MLP GEMM machinery (unchanged, proven) ----

#define STAGE(A_, Bt_, K_, k0_, b_)                                            \
    {                                                                          \
        const int row = tid >> 2, kc = tid & 3;                                \
        gll16((A_)  + (size_t)(m0 + row) * (K_) + (k0_) + kc * 8,              \
              (void*)&As[b_][tid * 8]);                                        \
        gll16((Bt_) + (size_t)(n0 + row) * (K_) + (k0_) + kc * 8,              \
              (void*)&Bs[b_][tid * 8]);                                        \
    }

#define GEMM_CORE(A_, Bt_, K_)                                                 \
    STAGE(A_, Bt_, K_, 0, 0)                                                   \
    {                                                                          \
        const int niter = (K_) / 32;                                           \
        for (int it = 0; it < niter; ++it) {                                   \
            __syncthreads();                                                   \
            if (it + 1 < niter) {                                              \
                const int kn = (it + 1) * 32, bn = (it + 1) & 1;               \
                STAGE(A_, Bt_, K_, kn, bn)                                     \
            }                                                                  \
            const unsigned short* Asb = As[it & 1];                            \
            const unsigned short* Bsb = Bs[it & 1];                            \
            bf16x8 aF[2], bF[4];                                               \
            _Pragma("unroll")                                                  \
            for (int mi = 0; mi < 2; ++mi)                                     \
                aF[mi] = *(const bf16x8*)(Asb + (wr*32 + mi*16 + lm)*32 + quad*8);\
            _Pragma("unroll")                                                  \
            for (int ni = 0; ni < 4; ++ni)                                     \
                bF[ni] = *(const bf16x8*)(Bsb + (wc*64 + ni*16 + lm)*32 + quad*8);\
            _Pragma("unroll")                                                  \
            for (int mi = 0; mi < 2; ++mi)                                     \
                _Pragma("unroll")                                              \
                for (int ni = 0; ni < 4; ++ni)                                 \
                    acc[mi][ni] = __builtin_amdgcn_mfma_f32_16x16x32_bf16(     \
                        aF[mi], bF[ni], acc[mi][ni], 0, 0, 0);                 \
        }                                                                      \
    }

#define GEMM_PREAMBLE                                                          \
    __shared__ __attribute__((aligned(16))) unsigned short As[2][128 * 32];    \
    __shared__ __attribute__((aligned(16))) unsigned short Bs[2][128 * 32];    \
    const int tid  = threadIdx.x;                                              \
    const int lane = tid & 63;                                                 \
    const int w    = tid >> 6;          /* 0..7 */                             \
    const int wr   = w >> 1, wc = w & 1; /* 4x2 wave grid */                   \
    const int lm   = lane & 15, quad = lane >> 4;                              \
    const int m0   = blockIdx.x * 128, n0 = blockIdx.y * 128;                  \
    f32x4 acc[2][4] = {};

template <int EPI, int OUT_BF16, int NGUARD>
__global__ __launch_bounds__(512, 6)
void gemm_mfma(const unsigned short* __restrict__ A,
               const unsigned short* __restrict__ Bt,
               const float* __restrict__ bias,
               void* __restrict__ Cv, int ldc, int Nreal, int K)
{
    GEMM_PREAMBLE
    GEMM_CORE(A, Bt, K)
    #pragma unroll
    for (int mi = 0; mi < 2; ++mi)
        #pragma unroll
        for (int r = 0; r < 4; ++r) {
            const size_t row = m0 + wr * 32 + mi * 16 + quad * 4 + r;
            #pragma unroll
            for (int ni = 0; ni < 4; ++ni) {
                const int col = n0 + wc * 64 + ni * 16 + lm;
                if (!NGUARD || col < Nreal) {
                    float v = acc[mi][ni][r] + bias[col];
                    if (EPI == EPI_RELU) v = fmaxf(v, 0.f);
                    if (EPI == EPI_TANH) v = tanhfast(v);
                    if (OUT_BF16) ((unsigned short*)Cv)[row * ldc + col] = f2bf(v);
                    else          ((float*)Cv)[row * ldc + col] = v;
                }
            }
        }
}

// ---- LSTM weight pack (enc+dec in one launch; blockIdx.y selects) ----
// kk-major, lane-major fragment layout (UNCHANGED):
//   elem(np, k) -> kk*49152 + frag*512 + (quad*16+lm)*8 + j   (shorts)
// frag = np>>4 (= ug*4+gate), k = kk*32+quad*8+j. Kp=448 both (dec k>=401
// zero-padded).
struct PackArgs {
    const float *Wa0, *Wb0, *bias0; unsigned short* Wt0; float* bI0; int K10, K0, Kp0;
    const float *Wa1, *Wb1, *bias1; unsigned short* Wt1; float* bI1; int K11, K1, Kp1;
};
__global__ void pack_lstm2(PackArgs p)
{
    const float* Wa  = blockIdx.y ? p.Wa1  : p.Wa0;
    const float* Wb  = blockIdx.y ? p.Wb1  : p.Wb0;
    const float* bias= blockIdx.y ? p.bias1: p.bias0;
    unsigned short* Wt = blockIdx.y ? p.Wt1 : p.Wt0;
    float* biasI = blockIdx.y ? p.bI1 : p.bI0;
    const int K1 = blockIdx.y ? p.K11 : p.K10;
    const int K  = blockIdx.y ? p.K1  : p.K0;
    const int Kp = blockIdx.y ? p.Kp1 : p.Kp0;
    const int idx = blockIdx.x * 256 + threadIdx.x;
    if (idx >= 1536 * Kp) return;
    const int np = idx / Kp, k = idx - np * Kp;
    const int ub = np >> 6, g = (np >> 4) & 3, ul = np & 15;
    const int u = ub * 16 + ul;
    const bool valid = (u < 356);
    const int norig = g * 356 + u;
    float v = 0.f;
    if (valid && k < K)
        v = (k < K1) ? Wa[(size_t)k * 1424 + norig]
                     : Wb[(size_t)(k - K1) * 1424 + norig];
    // kk-major, lane-major fragment layout
    const int wv = np / 192, rem = np - wv * 192;
    const int ni = rem >> 4, lmv = rem & 15;
    const int kkv = k >> 5, kq = k & 31;
    const int qd = kq >> 3, j = kq & 7;
    Wt[(size_t)kkv * 49152 + (size_t)(wv * 12 + ni) * 512 + (qd * 16 + lmv) * 8 + j]
        = f2bf(v);
    if (k == 0) biasI[np] = valid ? bias[norig] : 0.f;
}

// ---- MLP weight transpose+pack (fp32 [K][N] -> bf16 [Np][Kp]) ----
__global__ void transpose_pack(const float* __restrict__ W, int K, int N,
                               unsigned short* __restrict__ Wt, int Kp, int Np)
{
    __shared__ float t[32][33];
    const int n0 = blockIdx.x * 32, k0 = blockIdx.y * 32;
    const int tx = threadIdx.x, ty = threadIdx.y;
    #pragma unroll
    for (int r = 0; r < 4; ++r) {
        const int k = k0 + ty + 8 * r, n = n0 + tx;
        t[ty + 8 * r][tx] = (k < K && n < N) ? W[(size_t)k * N + n] : 0.f;
    }
    __syncthreads();
    #pragma unroll
    for (int r = 0; r < 4; ++r) {
        const int k = k0 + tx, n = n0 + ty + 8 * r;
        if (k < Kp && n < Np) Wt[(size_t)n * Kp + k] = f2bf(t[tx][ty + 8 * r]);
    }
}

// three 1024x1024 transposes in one launch (blockIdx.z selects)
struct WP3 { const float *s0, *s1, *s2; unsigned short *d0, *d1, *d2; };
__global__ void transpose_pack3(WP3 p)
{
    __shared__ float t[32][33];
    const float* W = (blockIdx.z == 0) ? p.s0 : (blockIdx.z == 1) ? p.s1 : p.s2;
    unsigned short* Wt = (blockIdx.z == 0) ? p.d0 : (blockIdx.z == 1) ? p.d1 : p.d2;
    const int n0 = blockIdx.x * 32, k0 = blockIdx.y * 32;
    const int tx = threadIdx.x, ty = threadIdx.y;
    #pragma unroll
    for (int r = 0; r < 4; ++r)
        t[ty + 8 * r][tx] = W[(size_t)(k0 + ty + 8 * r) * 1024 + n0 + tx];
    __syncthreads();
    #pragma unroll
    for (int r = 0; r < 4; ++r)
        Wt[(size_t)(n0 + ty + 8 * r) * 1024 + k0 + tx] = f2bf(t[tx][ty + 8 * r]);
}

// ---- zero dcd pad cols (2492..2495 of each row) ----
__global__ void zero_dcd_pad(unsigned short* __restrict__ dcd)
{
    const int i = blockIdx.x * 256 + threadIdx.x;
    if (i < 8192 * 4) dcd[(size_t)(i >> 2) * 2496 + 2492 + (i & 3)] = 0;
}

extern "C" void kernel_launch(void* const* d_in, const int* in_sizes, int n_in,
                              void* d_out, int out_size, void* d_ws, size_t ws_size,
                              hipStream_t stream)
{
    const float* x     = (const float*)d_in[0];
    const float* m     = (const float*)d_in[1];
    const float* enc_W = (const float*)d_in[2];
    const float* enc_U = (const float*)d_in[3];
    const float* enc_b = (const float*)d_in[4];
    const float* dec_W = (const float*)d_in[5];
    const float* dec_Um= (const float*)d_in[6];
    const float* dec_b = (const float*)d_in[7];
    const float* W_map = (const float*)d_in[8];
    const float* b_map = (const float*)d_in[9];
    const float* W1    = (const float*)d_in[10];
    const float* b1    = (const float*)d_in[11];
    const float* W2    = (const float*)d_in[12];
    const float* b2    = (const float*)d_in[13];
    const float* W3    = (const float*)d_in[14];
    const float* b3    = (const float*)d_in[15];
    const float* W_out = (const float*)d_in[16];
    const float* b_out = (const float*)d_in[17];
    float* out = (float*)d_out;

    const int B = 8192, FE = 69, FD = 45;
    const int KMP = 2496;

    char* ws = (char*)d_ws;
    size_t off = 0;
    auto alloc = [&](size_t bytes) -> void* {
        void* p = ws + off; off = (off + bytes + 255) & ~(size_t)255; return p;
    };
    unsigned short* WtE = (unsigned short*)alloc((size_t)1536 * 448 * 2);
    unsigned short* WtD = (unsigned short*)alloc((size_t)1536 * 448 * 2);
    unsigned short* WtM = (unsigned short*)alloc((size_t)1024 * KMP * 2);
    unsigned short* Wt1 = (unsigned short*)alloc((size_t)1024 * 1024 * 2);
    unsigned short* Wt2 = (unsigned short*)alloc((size_t)1024 * 1024 * 2);
    unsigned short* Wt3 = (unsigned short*)alloc((size_t)1024 * 1024 * 2);
    unsigned short* WtO = (unsigned short*)alloc((size_t)256 * 1024 * 2);
    float* bIE = (float*)alloc(1536 * 4);
    float* bID = (float*)alloc(1536 * 4);
    unsigned short* dcd = (unsigned short*)alloc((size_t)B * KMP * 2);
    unsigned short* a1  = (unsigned short*)alloc((size_t)B * 1024 * 2);
    unsigned short* a2  = (unsigned short*)alloc((size_t)B * 1024 * 2);

    // ---- weight packing (Kp=448 both, kk-major lane-major frags) ----
    PackArgs pa{enc_W, enc_U, enc_b, WtE, bIE, FE, FE + 356, 448,
                dec_W, dec_Um, dec_b, WtD, bID, FD, FD + 356, 448};
    pack_lstm2<<<dim3((1536 * 448 + 255) / 256, 2), 256, 0, stream>>>(pa);
    const dim3 tb(32, 8);
    transpose_pack<<<dim3(1024 / 32, KMP / 32), tb, 0, stream>>>(
        W_map, 2492, 1024, WtM, KMP, 1024);
    WP3 p3{W1, W2, W3, Wt1, Wt2, Wt3};
    transpose_pack3<<<dim3(32, 32, 3), tb, 0, stream>>>(p3);
    transpose_pack<<<dim3(256 / 32, 1024 / 32), tb, 0, stream>>>(
        W_out, 1024, 168, WtO, 1024, 256);
    zero_dcd_pad<<<(8192 * 4 + 255) / 256, 256, 0, stream>>>(dcd);

    // ---- persistent LSTM: one plain launch, zero grid sync ----
    lstm_persist<<<256, 768, 0, stream>>>(x, m, WtE, WtD, bIE, bID, dcd);

    // ---- MLP head ----
    gemm_mfma<EPI_RELU, 1, 0><<<dim3(64, 8), 512, 0, stream>>>(
        dcd, WtM, b_map, a1, 1024, 1024, KMP);
    gemm_mfma<EPI_TANH, 1, 0><<<dim3(64, 8), 512, 0, stream>>>(
        a1, Wt1, b1, a2, 1024, 1024, 1024);
    gemm_mfma<EPI_TANH, 1, 0><<<dim3(64, 8), 512, 0, stream>>>(
        a2, Wt2, b2, a1, 1024, 1024, 1024);
    gemm_mfma<EPI_TANH, 1, 0><<<dim3(64, 8), 512, 0, stream>>>(
        a1, Wt3, b3, a2, 1024, 1024, 1024);
    gemm_mfma<EPI_NONE, 0, 1><<<dim3(64, 2), 512, 0, stream>>>(
        a2, WtO, b_out, out, 168, 168, 1024);
}

// Round 15
// 553.270 us; speedup vs baseline: 1.2519x; 1.0028x over previous
//
#include <hip/hip_runtime.h>
#include <math.h>

// ---------------------------------------------------------------------------
// Round 24: harvest the step-boundary bubble. r23 post-mortem: 3 waves/SIMD
// (34% occ, no spill) changed NOTHING (340 vs 344/347) -> three-way
// invariance across TLP/pipeline/path => chain is L2-BW-saturated on
// 32x-duplicated weight reads (43 MB/step/XCD ~ observed 24.3us/step).
// PROWS=64 (halves duplication) is register-infeasible; fp8 risks absmax.
// This round: (a) pre-issue next step's first 2 weight chunks right after
// the post-loop barrier -> they fly during epilogue + x/m staging and are
// drained at the next entry barrier (wave-private buffers, vmcnt-safe
// either way); (b) hoist staging div-by-69/45 out of the step loop into
// named static per-thread constants. Everything else identical to r23.
// Decision rule: chain within +-2% of 340 => pattern ceiling declared.
// ---------------------------------------------------------------------------

using bf16x8 = __attribute__((ext_vector_type(8))) short;
using f32x4  = __attribute__((ext_vector_type(4))) float;

enum { EPI_NONE = 0, EPI_RELU = 1, EPI_TANH = 2 };

__device__ inline unsigned short f2bf(float f) {
    union { float f; unsigned u; } v; v.f = f;
    unsigned r = v.u + 0x7FFFu + ((v.u >> 16) & 1u);
    return (unsigned short)(r >> 16);
}
__device__ inline float sigf(float x) {
    return __fdividef(1.f, 1.f + __expf(-x));
}
__device__ inline float tanhfast(float x) {
    return 1.f - __fdividef(2.f, 1.f + __expf(2.f * x));
}

__device__ inline void gll16(const void* g, void* l) {
    __builtin_amdgcn_global_load_lds(
        (const __attribute__((address_space(1))) unsigned int*)(uintptr_t)g,
        (__attribute__((address_space(3))) unsigned int*)(unsigned int)(uintptr_t)l,
        16, 0, 0);
}

// ---------------------------------------------------------------------------
// Persistent LSTM: grid 256 x 768 threads (12 waves), 3 waves/SIMD
// (pinned by the 125.5KB LDS footprint -> 1 block/CU).
// Block b owns batch rows [32b, 32b+32). Ab [32][456] bf16 holds x|h.
// Wave w (0..11) owns packed fragments [8w, 8w+8) per kk = unit-groups
// {2w, 2w+1}; all 32 rows.
// Weight layout (pack_lstm2, kk-major lane-major): elem(frag, k=kk*32+
// quad*8+j) at kk*49152 + frag*512 + (quad*16+lm)*8 + j.
// Bs: per-wave 2 private buffers of 4 frags (4KB):
//   Bs[((w*2+buf)*4+q)*512 + lane*8]  (gll16 dest; ds_read lane*16B).
// ---------------------------------------------------------------------------
#define PROWS 32
#define PLDA  456

// stage chunk (kkv, partv) of weight set Wt_ -> per-wave buffer bufv
#define STAGE_CHUNK(Wt_, bufv, kkv, partv)                                     \
    _Pragma("unroll")                                                          \
    for (int q = 0; q < 4; ++q)                                                \
        gll16((Wt_) + (size_t)(kkv) * 49152 + (w * 8 + (partv) * 4 + q) * 512  \
                  + lane * 8,                                                  \
              (void*)&Bs[((w * 2 + (bufv)) * 4 + q) * 512 + lane * 8]);

// read the 4 fragments of per-wave buffer bufv (conflict-free lane*16B)
#define LOADB4(dst, bufv)                                                      \
    _Pragma("unroll")                                                          \
    for (int q = 0; q < 4; ++q)                                                \
        dst[q] = *(const bf16x8*)&Bs[((w * 2 + (bufv)) * 4 + q) * 512          \
                                     + lane * 8];

// load the 2 A-fragments for K-slice kkv from Ab
#define LOADA(dst, kkv)                                                        \
    _Pragma("unroll")                                                          \
    for (int mi = 0; mi < 2; ++mi)                                             \
        dst[mi] = *(const bf16x8*)&Ab[(mi * 16 + lm) * PLDA + (kkv) * 32       \
                                      + quad * 8];

// 8 MFMAs for part partv (LITERAL 0/1 -> static acc indices)
#define MFMA8(partv, bRv)                                                      \
    _Pragma("unroll")                                                          \
    for (int q = 0; q < 4; ++q) {                                              \
        acc[0][(partv) * 4 + q] = __builtin_amdgcn_mfma_f32_16x16x32_bf16(     \
            aF[0], bRv[q], acc[0][(partv) * 4 + q], 0, 0, 0);                  \
        acc[1][(partv) * 4 + q] = __builtin_amdgcn_mfma_f32_16x16x32_bf16(     \
            aF[1], bRv[q], acc[1][(partv) * 4 + q], 0, 0, 0);                  \
    }

#define VMWAIT(n)                                                              \
    asm volatile("s_waitcnt vmcnt(" #n ")" ::: "memory");                      \
    __builtin_amdgcn_sched_barrier(0);

__global__ __attribute__((amdgpu_flat_work_group_size(768, 768)))
void lstm_persist(const float* __restrict__ x,
                  const float* __restrict__ m,
                  const unsigned short* __restrict__ WtE,
                  const unsigned short* __restrict__ WtD,
                  const float* __restrict__ bIE,
                  const float* __restrict__ bID,
                  unsigned short* __restrict__ dcd)
{
    __shared__ __attribute__((aligned(16))) unsigned short Ab[PROWS * PLDA];
    __shared__ __attribute__((aligned(16))) unsigned short Bs[49152];
    const int tid  = threadIdx.x;
    const int lane = tid & 63;
    const int w    = tid >> 6;           // 0..11
    const int lm   = lane & 15, quad = lane >> 4;
    const int brow = blockIdx.x * PROWS;
    const int kk0  = blockIdx.x % 14;    // per-block kk stagger (L2 spread)

    // step-invariant staging indices (static names -> registers, rule #20)
    const int i1 = tid + 768, i2 = tid + 1536;
    const int rx0 = tid / 69, fx0 = tid - rx0 * 69;
    const int rx1 = i1 / 69,  fx1 = i1 - rx1 * 69;
    const int rx2 = i2 / 69,  fx2 = i2 - rx2 * 69;
    const bool vx1 = (i1 < PROWS * 69), vx2 = (i2 < PROWS * 69);
    const int rm0 = tid / 45, fm0 = tid - rm0 * 45;
    const int rm1 = i1 / 45,  fm1 = i1 - rm1 * 45;
    const bool vm1 = (i1 < PROWS * 45);

    // zero A-buffer (pads stay 0 forever), then stage x slice t=0
    for (int i = tid; i < PROWS * PLDA; i += 768) Ab[i] = 0;
    __syncthreads();
    Ab[rx0 * PLDA + fx0] = f2bf(x[((size_t)(brow + rx0) * 7 + 0) * 69 + fx0]);
    if (vx1) Ab[rx1 * PLDA + fx1] =
        f2bf(x[((size_t)(brow + rx1) * 7 + 0) * 69 + fx1]);
    if (vx2) Ab[rx2 * PLDA + fx2] =
        f2bf(x[((size_t)(brow + rx2) * 7 + 0) * 69 + fx2]);

    // prefetch step-0 weight chunks (drained at the s=0 entry barrier)
    STAGE_CHUNK(WtE, 0, kk0, 0)
    STAGE_CHUNK(WtE, 1, kk0, 1)

    float creg[2][2][4] = {};   // cell state: [mi][uu][r], unit (2w+uu)*16+lm
    float bI[2][4];             // bias: [uu][gate]

    for (int s = 0; s < 14; ++s) {
        const bool enc = (s < 7);
        const int t = enc ? s : s - 7;
        const unsigned short* Wt = enc ? WtE : WtD;

        if (s == 0 || s == 7) {
            const float* bsrc = enc ? bIE : bID;
            #pragma unroll
            for (int uu = 0; uu < 2; ++uu)
                #pragma unroll
                for (int g = 0; g < 4; ++g)
                    bI[uu][g] = bsrc[(2 * w + uu) * 64 + g * 16 + lm];
        }

        __syncthreads();   // Ab visible + prefetched chunks drained into Bs

        f32x4 acc[2][8] = {};
        {
            int kkc = kk0;
            #pragma unroll 1
            for (int i = 0; i < 14; ++i) {
                const int kkn = (kkc == 13) ? 0 : kkc + 1;
                bf16x8 aF[2], bR[4];
                // part 0: chunk(i,0) ready; compute buf0; stage (i+1,0)
                VMWAIT(4)
                LOADA(aF, kkc)
                LOADB4(bR, 0)
                MFMA8(0, bR)
                if (i < 13) STAGE_CHUNK(Wt, 0, kkn, 0)
                // part 1: chunk(i,1) ready; compute buf1; stage (i+1,1)
                if (i < 13) {
                    VMWAIT(4)
                } else {
                    VMWAIT(0)
                }
                LOADB4(bR, 1)
                MFMA8(1, bR)
                if (i < 13) STAGE_CHUNK(Wt, 1, kkn, 1)
                kkc = kkn;
            }
        }

        __syncthreads();   // all Ab reads done before h overwrite

        // prefetch NEXT step's first chunks: they fly during the epilogue +
        // x/m staging below and are drained at the next entry barrier.
        // Wave-private buffers -> no cross-wave hazard.
        if (s < 13) {
            const unsigned short* Wtn = (s + 1 < 7) ? WtE : WtD;
            STAGE_CHUNK(Wtn, 0, kk0, 0)
            STAGE_CHUNK(Wtn, 1, kk0, 1)
        }

        // epilogue: gates -> c (regs) -> h -> Ab[hoff+u] (+ dcd in dec phase)
        const int hoff = (s < 6) ? 69 : 45;   // layout of step s+1
        #pragma unroll
        for (int mi = 0; mi < 2; ++mi)
            #pragma unroll
            for (int uu = 0; uu < 2; ++uu) {
                const int u = (2 * w + uu) * 16 + lm;
                const bool uok = (u < 356);
                #pragma unroll
                for (int r = 0; r < 4; ++r) {
                    const float zi = acc[mi][uu * 4 + 0][r] + bI[uu][0];
                    const float zf = acc[mi][uu * 4 + 1][r] + bI[uu][1];
                    const float zg = acc[mi][uu * 4 + 2][r] + bI[uu][2];
                    const float zo = acc[mi][uu * 4 + 3][r] + bI[uu][3];
                    const float cn = sigf(zf) * creg[mi][uu][r]
                                   + sigf(zi) * tanhfast(zg);
                    creg[mi][uu][r] = cn;
                    const unsigned short hb = f2bf(sigf(zo) * tanhfast(cn));
                    const int rl = mi * 16 + quad * 4 + r;
                    if (uok) {
                        if (s < 13) Ab[rl * PLDA + hoff + u] = hb;
                        if (!enc)
                            dcd[(size_t)(brow + rl) * 2496 + t * 356 + u] = hb;
                    }
                }
            }

        // stage x/m slice for step s+1 (disjoint from h region)
        const int sn = s + 1;
        if (sn < 7) {
            Ab[rx0 * PLDA + fx0] =
                f2bf(x[((size_t)(brow + rx0) * 7 + sn) * 69 + fx0]);
            if (vx1) Ab[rx1 * PLDA + fx1] =
                f2bf(x[((size_t)(brow + rx1) * 7 + sn) * 69 + fx1]);
            if (vx2) Ab[rx2 * PLDA + fx2] =
                f2bf(x[((size_t)(brow + rx2) * 7 + sn) * 69 + fx2]);
        } else if (sn < 14) {
            const int tm = sn - 7;
            Ab[rm0 * PLDA + fm0] =
                f2bf(m[((size_t)(brow + rm0) * 7 + tm) * 45 + fm0]);
            if (vm1) Ab[rm1 * PLDA + fm1] =
                f2bf(m[((size_t)(brow + rm1) * 7 + tm) * 45 + fm1]);
        }
    }
}

// ---- MLP GEMM machinery (unchanged, proven) ----

#define STAGE(A_, Bt_, K_, k0_, b_)                                            \
    {                                                                          \
        const int row = tid >> 2, kc = tid & 3;                                \
        gll16((A_)  + (size_t)(m0 + row) * (K_) + (k0_) + kc * 8,              \
              (void*)&As[b_][tid * 8]);                                        \
        gll16((Bt_) + (size_t)(n0 + row) * (K_) + (k0_) + kc * 8,              \
              (void*)&Bs[b_][tid * 8]);                                        \
    }

#define GEMM_CORE(A_, Bt_, K_)                                                 \
    STAGE(A_, Bt_, K_, 0, 0)                                                   \
    {                                                                          \
        const int niter = (K_) / 32;                                           \
        for (int it = 0; it < niter; ++it) {                                   \
            __syncthreads();                                                   \
            if (it + 1 < niter) {                                              \
                const int kn = (it + 1) * 32, bn = (it + 1) & 1;               \
                STAGE(A_, Bt_, K_, kn, bn)                                     \
            }                                                                  \
            const unsigned short* Asb = As[it & 1];                            \
            const unsigned short* Bsb = Bs[it & 1];                            \
            bf16x8 aF[2], bF[4];                                               \
            _Pragma("unroll")                                                  \
            for (int mi = 0; mi < 2; ++mi)                                     \
                aF[mi] = *(const bf16x8*)(Asb + (wr*32 + mi*16 + lm)*32 + quad*8);\
            _Pragma("unroll")                                                  \
            for (int ni = 0; ni < 4; ++ni)                                     \
                bF[ni] = *(const bf16x8*)(Bsb + (wc*64 + ni*16 + lm)*32 + quad*8);\
            _Pragma("unroll")                                                  \
            for (int mi = 0; mi < 2; ++mi)                                     \
                _Pragma("unroll")                                              \
                for (int ni = 0; ni < 4; ++ni)                                 \
                    acc[mi][ni] = __builtin_amdgcn_mfma_f32_16x16x32_bf16(     \
                        aF[mi], bF[ni], acc[mi][ni], 0, 0, 0);                 \
        }                                                                      \
    }

#define GEMM_PREAMBLE                                                          \
    __shared__ __attribute__((aligned(16))) unsigned short As[2][128 * 32];    \
    __shared__ __attribute__((aligned(16))) unsigned short Bs[2][128 * 32];    \
    const int tid  = threadIdx.x;                                              \
    const int lane = tid & 63;                                                 \
    const int w    = tid >> 6;          /* 0..7 */                             \
    const int wr   = w >> 1, wc = w & 1; /* 4x2 wave grid */                   \
    const int lm   = lane & 15, quad = lane >> 4;                              \
    const int m0   = blockIdx.x * 128, n0 = blockIdx.y * 128;                  \
    f32x4 acc[2][4] = {};

template <int EPI, int OUT_BF16, int NGUARD>
__global__ __launch_bounds__(512, 6)
void gemm_mfma(const unsigned short* __restrict__ A,
               const unsigned short* __restrict__ Bt,
               const float* __restrict__ bias,
               void* __restrict__ Cv, int ldc, int Nreal, int K)
{
    GEMM_PREAMBLE
    GEMM_CORE(A, Bt, K)
    #pragma unroll
    for (int mi = 0; mi < 2; ++mi)
        #pragma unroll
        for (int r = 0; r < 4; ++r) {
            const size_t row = m0 + wr * 32 + mi * 16 + quad * 4 + r;
            #pragma unroll
            for (int ni = 0; ni < 4; ++ni) {
                const int col = n0 + wc * 64 + ni * 16 + lm;
                if (!NGUARD || col < Nreal) {
                    float v = acc[mi][ni][r] + bias[col];
                    if (EPI == EPI_RELU) v = fmaxf(v, 0.f);
                    if (EPI == EPI_TANH) v = tanhfast(v);
                    if (OUT_BF16) ((unsigned short*)Cv)[row * ldc + col] = f2bf(v);
                    else          ((float*)Cv)[row * ldc + col] = v;
                }
            }
        }
}

// ---- LSTM weight pack (enc+dec in one launch; blockIdx.y selects) ----
// kk-major, lane-major fragment layout (UNCHANGED):
//   elem(np, k) -> kk*49152 + frag*512 + (quad*16+lm)*8 + j   (shorts)
// frag = np>>4 (= ug*4+gate), k = kk*32+quad*8+j. Kp=448 both (dec k>=401
// zero-padded).
struct PackArgs {
    const float *Wa0, *Wb0, *bias0; unsigned short* Wt0; float* bI0; int K10, K0, Kp0;
    const float *Wa1, *Wb1, *bias1; unsigned short* Wt1; float* bI1; int K11, K1, Kp1;
};
__global__ void pack_lstm2(PackArgs p)
{
    const float* Wa  = blockIdx.y ? p.Wa1  : p.Wa0;
    const float* Wb  = blockIdx.y ? p.Wb1  : p.Wb0;
    const float* bias= blockIdx.y ? p.bias1: p.bias0;
    unsigned short* Wt = blockIdx.y ? p.Wt1 : p.Wt0;
    float* biasI = blockIdx.y ? p.bI1 : p.bI0;
    const int K1 = blockIdx.y ? p.K11 : p.K10;
    const int K  = blockIdx.y ? p.K1  : p.K0;
    const int Kp = blockIdx.y ? p.Kp1 : p.Kp0;
    const int idx = blockIdx.x * 256 + threadIdx.x;
    if (idx >= 1536 * Kp) return;
    const int np = idx / Kp, k = idx - np * Kp;
    const int ub = np >> 6, g = (np >> 4) & 3, ul = np & 15;
    const int u = ub * 16 + ul;
    const bool valid = (u < 356);
    const int norig = g * 356 + u;
    float v = 0.f;
    if (valid && k < K)
        v = (k < K1) ? Wa[(size_t)k * 1424 + norig]
                     : Wb[(size_t)(k - K1) * 1424 + norig];
    // kk-major, lane-major fragment layout
    const int wv = np / 192, rem = np - wv * 192;
    const int ni = rem >> 4, lmv = rem & 15;
    const int kkv = k >> 5, kq = k & 31;
    const int qd = kq >> 3, j = kq & 7;
    Wt[(size_t)kkv * 49152 + (size_t)(wv * 12 + ni) * 512 + (qd * 16 + lmv) * 8 + j]
        = f2bf(v);
    if (k == 0) biasI[np] = valid ? bias[norig] : 0.f;
}

// ---- MLP weight transpose+pack (fp32 [K][N] -> bf16 [Np][Kp]) ----
__global__ void transpose_pack(const float* __restrict__ W, int K, int N,
                               unsigned short* __restrict__ Wt, int Kp, int Np)
{
    __shared__ float t[32][33];
    const int n0 = blockIdx.x * 32, k0 = blockIdx.y * 32;
    const int tx = threadIdx.x, ty = threadIdx.y;
    #pragma unroll
    for (int r = 0; r < 4; ++r) {
        const int k = k0 + ty + 8 * r, n = n0 + tx;
        t[ty + 8 * r][tx] = (k < K && n < N) ? W[(size_t)k * N + n] : 0.f;
    }
    __syncthreads();
    #pragma unroll
    for (int r = 0; r < 4; ++r) {
        const int k = k0 + tx, n = n0 + ty + 8 * r;
        if (k < Kp && n < Np) Wt[(size_t)n * Kp + k] = f2bf(t[tx][ty + 8 * r]);
    }
}

// three 1024x1024 transposes in one launch (blockIdx.z selects)
struct WP3 { const float *s0, *s1, *s2; unsigned short *d0, *d1, *d2; };
__global__ void transpose_pack3(WP3 p)
{
    __shared__ float t[32][33];
    const float* W = (blockIdx.z == 0) ? p.s0 : (blockIdx.z == 1) ? p.s1 : p.s2;
    unsigned short* Wt = (blockIdx.z == 0) ? p.d0 : (blockIdx.z == 1) ? p.d1 : p.d2;
    const int n0 = blockIdx.x * 32, k0 = blockIdx.y * 32;
    const int tx = threadIdx.x, ty = threadIdx.y;
    #pragma unroll
    for (int r = 0; r < 4; ++r)
        t[ty + 8 * r][tx] = W[(size_t)(k0 + ty + 8 * r) * 1024 + n0 + tx];
    __syncthreads();
    #pragma unroll
    for (int r = 0; r < 4; ++r)
        Wt[(size_t)(n0 + ty + 8 * r) * 1024 + k0 + tx] = f2bf(t[tx][ty + 8 * r]);
}

// ---- zero dcd pad cols (2492..2495 of each row) ----
__global__ void zero_dcd_pad(unsigned short* __restrict__ dcd)
{
    const int i = blockIdx.x * 256 + threadIdx.x;
    if (i < 8192 * 4) dcd[(size_t)(i >> 2) * 2496 + 2492 + (i & 3)] = 0;
}

extern "C" void kernel_launch(void* const* d_in, const int* in_sizes, int n_in,
                              void* d_out, int out_size, void* d_ws, size_t ws_size,
                              hipStream_t stream)
{
    const float* x     = (const float*)d_in[0];
    const float* m     = (const float*)d_in[1];
    const float* enc_W = (const float*)d_in[2];
    const float* enc_U = (const float*)d_in[3];
    const float* enc_b = (const float*)d_in[4];
    const float* dec_W = (const float*)d_in[5];
    const float* dec_Um= (const float*)d_in[6];
    const float* dec_b = (const float*)d_in[7];
    const float* W_map = (const float*)d_in[8];
    const float* b_map = (const float*)d_in[9];
    const float* W1    = (const float*)d_in[10];
    const float* b1    = (const float*)d_in[11];
    const float* W2    = (const float*)d_in[12];
    const float* b2    = (const float*)d_in[13];
    const float* W3    = (const float*)d_in[14];
    const float* b3    = (const float*)d_in[15];
    const float* W_out = (const float*)d_in[16];
    const float* b_out = (const float*)d_in[17];
    float* out = (float*)d_out;

    const int B = 8192, FE = 69, FD = 45;
    const int KMP = 2496;

    char* ws = (char*)d_ws;
    size_t off = 0;
    auto alloc = [&](size_t bytes) -> void* {
        void* p = ws + off; off = (off + bytes + 255) & ~(size_t)255; return p;
    };
    unsigned short* WtE = (unsigned short*)alloc((size_t)1536 * 448 * 2);
    unsigned short* WtD = (unsigned short*)alloc((size_t)1536 * 448 * 2);
    unsigned short* WtM = (unsigned short*)alloc((size_t)1024 * KMP * 2);
    unsigned short* Wt1 = (unsigned short*)alloc((size_t)1024 * 1024 * 2);
    unsigned short* Wt2 = (unsigned short*)alloc((size_t)1024 * 1024 * 2);
    unsigned short* Wt3 = (unsigned short*)alloc((size_t)1024 * 1024 * 2);
    unsigned short* WtO = (unsigned short*)alloc((size_t)256 * 1024 * 2);
    float* bIE = (float*)alloc(1536 * 4);
    float* bID = (float*)alloc(1536 * 4);
    unsigned short* dcd = (unsigned short*)alloc((size_t)B * KMP * 2);
    unsigned short* a1  = (unsigned short*)alloc((size_t)B * 1024 * 2);
    unsigned short* a2  = (unsigned short*)alloc((size_t)B * 1024 * 2);

    // ---- weight packing (Kp=448 both, kk-major lane-major frags) ----
    PackArgs pa{enc_W, enc_U, enc_b, WtE, bIE, FE, FE + 356, 448,
                dec_W, dec_Um, dec_b, WtD, bID, FD, FD + 356, 448};
    pack_lstm2<<<dim3((1536 * 448 + 255) / 256, 2), 256, 0, stream>>>(pa);
    const dim3 tb(32, 8);
    transpose_pack<<<dim3(1024 / 32, KMP / 32), tb, 0, stream>>>(
        W_map, 2492, 1024, WtM, KMP, 1024);
    WP3 p3{W1, W2, W3, Wt1, Wt2, Wt3};
    transpose_pack3<<<dim3(32, 32, 3), tb, 0, stream>>>(p3);
    transpose_pack<<<dim3(256 / 32, 1024 / 32), tb, 0, stream>>>(
        W_out, 1024, 168, WtO, 1024, 256);
    zero_dcd_pad<<<(8192 * 4 + 255) / 256, 256, 0, stream>>>(dcd);

    // ---- persistent LSTM: one plain launch, zero grid sync ----
    lstm_persist<<<256, 768, 0, stream>>>(x, m, WtE, WtD, bIE, bID, dcd);

    // ---- MLP head ----
    gemm_mfma<EPI_RELU, 1, 0><<<dim3(64, 8), 512, 0, stream>>>(
        dcd, WtM, b_map, a1, 1024, 1024, KMP);
    gemm_mfma<EPI_TANH, 1, 0><<<dim3(64, 8), 512, 0, stream>>>(
        a1, Wt1, b1, a2, 1024, 1024, 1024);
    gemm_mfma<EPI_TANH, 1, 0><<<dim3(64, 8), 512, 0, stream>>>(
        a2, Wt2, b2, a1, 1024, 1024, 1024);
    gemm_mfma<EPI_TANH, 1, 0><<<dim3(64, 8), 512, 0, stream>>>(
        a1, Wt3, b3, a2, 1024, 1024, 1024);
    gemm_mfma<EPI_NONE, 0, 1><<<dim3(64, 2), 512, 0, stream>>>(
        a2, WtO, b_out, out, 168, 168, 1024);
}

// Round 16
// 549.404 us; speedup vs baseline: 1.2607x; 1.0070x over previous
//
#include <hip/hip_runtime.h>
#include <math.h>

// ---------------------------------------------------------------------------
// Round 25: last chain lever — strength-reduce gll16 addressing. r24's
// step-boundary prefetch was null (343 vs 340, pre-registered band) -> the
// duplicate-broadcast L2 pattern holds at ~42% of per-XCD L2 BW across four
// structural variants. Un-probed: VALUBusy 49% vs MfmaUtil 20% — dynamic
// kkc (mod-14 rotation) defeats affine strength-reduction, so every gll16
// recomputes a full 64-bit address (~6 VALU x 8 addrs/kk) serially between
// VMWAIT and the next load burst. Fix: hoist per-thread invariant base
// (Wt + w*8*512 + lane*8) into 2 pointers; carry koff/aoff with one
// compare-select per kk; every address = base + koff + IMM. Schedule,
// buffers, vmcnt, layout byte-identical to r24. Also: pack_lstm2 k-major
// thread map (reads 64B-coalesced, was stride-5.7KB).
// Decision rule: chain within +-2% of 343 -> declare pattern ceiling.
// ---------------------------------------------------------------------------

using bf16x8 = __attribute__((ext_vector_type(8))) short;
using f32x4  = __attribute__((ext_vector_type(4))) float;

enum { EPI_NONE = 0, EPI_RELU = 1, EPI_TANH = 2 };

__device__ inline unsigned short f2bf(float f) {
    union { float f; unsigned u; } v; v.f = f;
    unsigned r = v.u + 0x7FFFu + ((v.u >> 16) & 1u);
    return (unsigned short)(r >> 16);
}
__device__ inline float sigf(float x) {
    return __fdividef(1.f, 1.f + __expf(-x));
}
__device__ inline float tanhfast(float x) {
    return 1.f - __fdividef(2.f, 1.f + __expf(2.f * x));
}

__device__ inline void gll16(const void* g, void* l) {
    __builtin_amdgcn_global_load_lds(
        (const __attribute__((address_space(1))) unsigned int*)(uintptr_t)g,
        (__attribute__((address_space(3))) unsigned int*)(unsigned int)(uintptr_t)l,
        16, 0, 0);
}

// ---------------------------------------------------------------------------
// Persistent LSTM: grid 256 x 768 threads (12 waves), 3 waves/SIMD
// (pinned by the 125.5KB LDS footprint -> 1 block/CU).
// Block b owns batch rows [32b, 32b+32). Ab [32][456] bf16 holds x|h.
// Wave w (0..11) owns packed fragments [8w, 8w+8) per kk.
// Weight layout (pack_lstm2, kk-major lane-major): elem(frag, k=kk*32+
// quad*8+j) at kk*49152 + frag*512 + (quad*16+lm)*8 + j.
// Addressing: per-thread base wb = Wt + w*8*512 + lane*8 (hoisted);
// chunk addr = wb + koff + (part*4+q)*512, koff carried by compare-select.
// ---------------------------------------------------------------------------
#define PROWS 32
#define PLDA  456

// stage chunk (koff_, partv) from per-thread base wb_ -> per-wave buffer bufv
#define STAGE_CHUNK(wb_, bufv, koff_, partv)                                   \
    _Pragma("unroll")                                                          \
    for (int q = 0; q < 4; ++q)                                                \
        gll16((wb_) + (koff_) + ((partv) * 4 + q) * 512,                       \
              (void*)&Bs[((w * 2 + (bufv)) * 4 + q) * 512 + lane * 8]);

// read the 4 fragments of per-wave buffer bufv (conflict-free lane*16B)
#define LOADB4(dst, bufv)                                                      \
    _Pragma("unroll")                                                          \
    for (int q = 0; q < 4; ++q)                                                \
        dst[q] = *(const bf16x8*)&Bs[((w * 2 + (bufv)) * 4 + q) * 512          \
                                     + lane * 8];

// load the 2 A-fragments at carried short-offset aoff_ (= kk*32)
#define LOADA(dst, aoff_)                                                      \
    _Pragma("unroll")                                                          \
    for (int mi = 0; mi < 2; ++mi)                                             \
        dst[mi] = *(const bf16x8*)&Ab[(mi * 16 + lm) * PLDA + (aoff_)          \
                                      + quad * 8];

// 8 MFMAs for part partv (LITERAL 0/1 -> static acc indices)
#define MFMA8(partv, bRv)                                                      \
    _Pragma("unroll")                                                          \
    for (int q = 0; q < 4; ++q) {                                              \
        acc[0][(partv) * 4 + q] = __builtin_amdgcn_mfma_f32_16x16x32_bf16(     \
            aF[0], bRv[q], acc[0][(partv) * 4 + q], 0, 0, 0);                  \
        acc[1][(partv) * 4 + q] = __builtin_amdgcn_mfma_f32_16x16x32_bf16(     \
            aF[1], bRv[q], acc[1][(partv) * 4 + q], 0, 0, 0);                  \
    }

#define VMWAIT(n)                                                              \
    asm volatile("s_waitcnt vmcnt(" #n ")" ::: "memory");                      \
    __builtin_amdgcn_sched_barrier(0);

__global__ __attribute__((amdgpu_flat_work_group_size(768, 768)))
void lstm_persist(const float* __restrict__ x,
                  const float* __restrict__ m,
                  const unsigned short* __restrict__ WtE,
                  const unsigned short* __restrict__ WtD,
                  const float* __restrict__ bIE,
                  const float* __restrict__ bID,
                  unsigned short* __restrict__ dcd)
{
    __shared__ __attribute__((aligned(16))) unsigned short Ab[PROWS * PLDA];
    __shared__ __attribute__((aligned(16))) unsigned short Bs[49152];
    const int tid  = threadIdx.x;
    const int lane = tid & 63;
    const int w    = tid >> 6;           // 0..11
    const int lm   = lane & 15, quad = lane >> 4;
    const int brow = blockIdx.x * PROWS;
    const int kk0  = blockIdx.x % 14;    // per-block kk stagger (L2 spread)

    // hoisted per-thread weight bases (step-invariant)
    const unsigned short* wbE = WtE + (w * 8) * 512 + lane * 8;
    const unsigned short* wbD = WtD + (w * 8) * 512 + lane * 8;
    const size_t koff0 = (size_t)kk0 * 49152;
    const int    aoff0 = kk0 * 32;

    // step-invariant staging indices (static names -> registers, rule #20)
    const int i1 = tid + 768, i2 = tid + 1536;
    const int rx0 = tid / 69, fx0 = tid - rx0 * 69;
    const int rx1 = i1 / 69,  fx1 = i1 - rx1 * 69;
    const int rx2 = i2 / 69,  fx2 = i2 - rx2 * 69;
    const bool vx1 = (i1 < PROWS * 69), vx2 = (i2 < PROWS * 69);
    const int rm0 = tid / 45, fm0 = tid - rm0 * 45;
    const int rm1 = i1 / 45,  fm1 = i1 - rm1 * 45;
    const bool vm1 = (i1 < PROWS * 45);

    // zero A-buffer (pads stay 0 forever), then stage x slice t=0
    for (int i = tid; i < PROWS * PLDA; i += 768) Ab[i] = 0;
    __syncthreads();
    Ab[rx0 * PLDA + fx0] = f2bf(x[((size_t)(brow + rx0) * 7 + 0) * 69 + fx0]);
    if (vx1) Ab[rx1 * PLDA + fx1] =
        f2bf(x[((size_t)(brow + rx1) * 7 + 0) * 69 + fx1]);
    if (vx2) Ab[rx2 * PLDA + fx2] =
        f2bf(x[((size_t)(brow + rx2) * 7 + 0) * 69 + fx2]);

    // prefetch step-0 weight chunks (drained at the s=0 entry barrier)
    STAGE_CHUNK(wbE, 0, koff0, 0)
    STAGE_CHUNK(wbE, 1, koff0, 1)

    float creg[2][2][4] = {};   // cell state: [mi][uu][r], unit (2w+uu)*16+lm
    float bI[2][4];             // bias: [uu][gate]

    for (int s = 0; s < 14; ++s) {
        const bool enc = (s < 7);
        const int t = enc ? s : s - 7;
        const unsigned short* wb = enc ? wbE : wbD;

        if (s == 0 || s == 7) {
            const float* bsrc = enc ? bIE : bID;
            #pragma unroll
            for (int uu = 0; uu < 2; ++uu)
                #pragma unroll
                for (int g = 0; g < 4; ++g)
                    bI[uu][g] = bsrc[(2 * w + uu) * 64 + g * 16 + lm];
        }

        __syncthreads();   // Ab visible + prefetched chunks drained into Bs

        f32x4 acc[2][8] = {};
        {
            size_t koff = koff0;
            int    aoff = aoff0;
            #pragma unroll 1
            for (int i = 0; i < 14; ++i) {
                const size_t knoff = (koff == (size_t)13 * 49152)
                                       ? 0 : koff + 49152;
                const int    anoff = (aoff == 13 * 32) ? 0 : aoff + 32;
                bf16x8 aF[2], bR[4];
                // part 0: chunk(i,0) ready; compute buf0; stage (i+1,0)
                VMWAIT(4)
                LOADA(aF, aoff)
                LOADB4(bR, 0)
                MFMA8(0, bR)
                if (i < 13) STAGE_CHUNK(wb, 0, knoff, 0)
                // part 1: chunk(i,1) ready; compute buf1; stage (i+1,1)
                if (i < 13) {
                    VMWAIT(4)
                } else {
                    VMWAIT(0)
                }
                LOADB4(bR, 1)
                MFMA8(1, bR)
                if (i < 13) STAGE_CHUNK(wb, 1, knoff, 1)
                koff = knoff; aoff = anoff;
            }
        }

        __syncthreads();   // all Ab reads done before h overwrite

        // prefetch NEXT step's first chunks: fly during epilogue + staging,
        // drained at the next entry barrier (wave-private buffers).
        if (s < 13) {
            const unsigned short* wbn = (s + 1 < 7) ? wbE : wbD;
            STAGE_CHUNK(wbn, 0, koff0, 0)
            STAGE_CHUNK(wbn, 1, koff0, 1)
        }

        // epilogue: gates -> c (regs) -> h -> Ab[hoff+u] (+ dcd in dec phase)
        const int hoff = (s < 6) ? 69 : 45;   // layout of step s+1
        #pragma unroll
        for (int mi = 0; mi < 2; ++mi)
            #pragma unroll
            for (int uu = 0; uu < 2; ++uu) {
                const int u = (2 * w + uu) * 16 + lm;
                const bool uok = (u < 356);
                #pragma unroll
                for (int r = 0; r < 4; ++r) {
                    const float zi = acc[mi][uu * 4 + 0][r] + bI[uu][0];
                    const float zf = acc[mi][uu * 4 + 1][r] + bI[uu][1];
                    const float zg = acc[mi][uu * 4 + 2][r] + bI[uu][2];
                    const float zo = acc[mi][uu * 4 + 3][r] + bI[uu][3];
                    const float cn = sigf(zf) * creg[mi][uu][r]
                                   + sigf(zi) * tanhfast(zg);
                    creg[mi][uu][r] = cn;
                    const unsigned short hb = f2bf(sigf(zo) * tanhfast(cn));
                    const int rl = mi * 16 + quad * 4 + r;
                    if (uok) {
                        if (s < 13) Ab[rl * PLDA + hoff + u] = hb;
                        if (!enc)
                            dcd[(size_t)(brow + rl) * 2496 + t * 356 + u] = hb;
                    }
                }
            }

        // stage x/m slice for step s+1 (disjoint from h region)
        const int sn = s + 1;
        if (sn < 7) {
            Ab[rx0 * PLDA + fx0] =
                f2bf(x[((size_t)(brow + rx0) * 7 + sn) * 69 + fx0]);
            if (vx1) Ab[rx1 * PLDA + fx1] =
                f2bf(x[((size_t)(brow + rx1) * 7 + sn) * 69 + fx1]);
            if (vx2) Ab[rx2 * PLDA + fx2] =
                f2bf(x[((size_t)(brow + rx2) * 7 + sn) * 69 + fx2]);
        } else if (sn < 14) {
            const int tm = sn - 7;
            Ab[rm0 * PLDA + fm0] =
                f2bf(m[((size_t)(brow + rm0) * 7 + tm) * 45 + fm0]);
            if (vm1) Ab[rm1 * PLDA + fm1] =
                f2bf(m[((size_t)(brow + rm1) * 7 + tm) * 45 + fm1]);
        }
    }
}

// ---- MLP GEMM machinery (unchanged, proven) ----

#define STAGE(A_, Bt_, K_, k0_, b_)                                            \
    {                                                                          \
        const int row = tid >> 2, kc = tid & 3;                                \
        gll16((A_)  + (size_t)(m0 + row) * (K_) + (k0_) + kc * 8,              \
              (void*)&As[b_][tid * 8]);                                        \
        gll16((Bt_) + (size_t)(n0 + row) * (K_) + (k0_) + kc * 8,              \
              (void*)&Bs[b_][tid * 8]);                                        \
    }

#define GEMM_CORE(A_, Bt_, K_)                                                 \
    STAGE(A_, Bt_, K_, 0, 0)                                                   \
    {                                                                          \
        const int niter = (K_) / 32;                                           \
        for (int it = 0; it < niter; ++it) {                                   \
            __syncthreads();                                                   \
            if (it + 1 < niter) {                                              \
                const int kn = (it + 1) * 32, bn = (it + 1) & 1;               \
                STAGE(A_, Bt_, K_, kn, bn)                                     \
            }                                                                  \
            const unsigned short* Asb = As[it & 1];                            \
            const unsigned short* Bsb = Bs[it & 1];                            \
            bf16x8 aF[2], bF[4];                                               \
            _Pragma("unroll")                                                  \
            for (int mi = 0; mi < 2; ++mi)                                     \
                aF[mi] = *(const bf16x8*)(Asb + (wr*32 + mi*16 + lm)*32 + quad*8);\
            _Pragma("unroll")                                                  \
            for (int ni = 0; ni < 4; ++ni)                                     \
                bF[ni] = *(const bf16x8*)(Bsb + (wc*64 + ni*16 + lm)*32 + quad*8);\
            _Pragma("unroll")                                                  \
            for (int mi = 0; mi < 2; ++mi)                                     \
                _Pragma("unroll")                                              \
                for (int ni = 0; ni < 4; ++ni)                                 \
                    acc[mi][ni] = __builtin_amdgcn_mfma_f32_16x16x32_bf16(     \
                        aF[mi], bF[ni], acc[mi][ni], 0, 0, 0);                 \
        }                                                                      \
    }

#define GEMM_PREAMBLE                                                          \
    __shared__ __attribute__((aligned(16))) unsigned short As[2][128 * 32];    \
    __shared__ __attribute__((aligned(16))) unsigned short Bs[2][128 * 32];    \
    const int tid  = threadIdx.x;                                              \
    const int lane = tid & 63;                                                 \
    const int w    = tid >> 6;          /* 0..7 */                             \
    const int wr   = w >> 1, wc = w & 1; /* 4x2 wave grid */                   \
    const int lm   = lane & 15, quad = lane >> 4;                              \
    const int m0   = blockIdx.x * 128, n0 = blockIdx.y * 128;                  \
    f32x4 acc[2][4] = {};

template <int EPI, int OUT_BF16, int NGUARD>
__global__ __launch_bounds__(512, 6)
void gemm_mfma(const unsigned short* __restrict__ A,
               const unsigned short* __restrict__ Bt,
               const float* __restrict__ bias,
               void* __restrict__ Cv, int ldc, int Nreal, int K)
{
    GEMM_PREAMBLE
    GEMM_CORE(A, Bt, K)
    #pragma unroll
    for (int mi = 0; mi < 2; ++mi)
        #pragma unroll
        for (int r = 0; r < 4; ++r) {
            const size_t row = m0 + wr * 32 + mi * 16 + quad * 4 + r;
            #pragma unroll
            for (int ni = 0; ni < 4; ++ni) {
                const int col = n0 + wc * 64 + ni * 16 + lm;
                if (!NGUARD || col < Nreal) {
                    float v = acc[mi][ni][r] + bias[col];
                    if (EPI == EPI_RELU) v = fmaxf(v, 0.f);
                    if (EPI == EPI_TANH) v = tanhfast(v);
                    if (OUT_BF16) ((unsigned short*)Cv)[row * ldc + col] = f2bf(v);
                    else          ((float*)Cv)[row * ldc + col] = v;
                }
            }
        }
}

// ---- LSTM weight pack (enc+dec in one launch; blockIdx.y selects) ----
// kk-major, lane-major fragment layout (UNCHANGED):
//   elem(np, k) -> kk*49152 + frag*512 + (quad*16+lm)*8 + j   (shorts)
// Thread map now k-major: consecutive threads -> consecutive np -> 64B-
// coalesced source reads (was stride-5.7KB, one line per lane).
struct PackArgs {
    const float *Wa0, *Wb0, *bias0; unsigned short* Wt0; float* bI0; int K10, K0, Kp0;
    const float *Wa1, *Wb1, *bias1; unsigned short* Wt1; float* bI1; int K11, K1, Kp1;
};
__global__ void pack_lstm2(PackArgs p)
{
    const float* Wa  = blockIdx.y ? p.Wa1  : p.Wa0;
    const float* Wb  = blockIdx.y ? p.Wb1  : p.Wb0;
    const float* bias= blockIdx.y ? p.bias1: p.bias0;
    unsigned short* Wt = blockIdx.y ? p.Wt1 : p.Wt0;
    float* biasI = blockIdx.y ? p.bI1 : p.bI0;
    const int K1 = blockIdx.y ? p.K11 : p.K10;
    const int K  = blockIdx.y ? p.K1  : p.K0;
    const int Kp = blockIdx.y ? p.Kp1 : p.Kp0;
    const int idx = blockIdx.x * 256 + threadIdx.x;
    if (idx >= 1536 * Kp) return;
    const int k = idx / 1536, np = idx - k * 1536;   // k-major: coalesced
    const int ub = np >> 6, g = (np >> 4) & 3, ul = np & 15;
    const int u = ub * 16 + ul;
    const bool valid = (u < 356);
    const int norig = g * 356 + u;
    float v = 0.f;
    if (valid && k < K)
        v = (k < K1) ? Wa[(size_t)k * 1424 + norig]
                     : Wb[(size_t)(k - K1) * 1424 + norig];
    // kk-major, lane-major fragment layout
    const int wv = np / 192, rem = np - wv * 192;
    const int ni = rem >> 4, lmv = rem & 15;
    const int kkv = k >> 5, kq = k & 31;
    const int qd = kq >> 3, j = kq & 7;
    Wt[(size_t)kkv * 49152 + (size_t)(wv * 12 + ni) * 512 + (qd * 16 + lmv) * 8 + j]
        = f2bf(v);
    if (k == 0) biasI[np] = valid ? bias[norig] : 0.f;
}

// ---- MLP weight transpose+pack (fp32 [K][N] -> bf16 [Np][Kp]) ----
__global__ void transpose_pack(const float* __restrict__ W, int K, int N,
                               unsigned short* __restrict__ Wt, int Kp, int Np)
{
    __shared__ float t[32][33];
    const int n0 = blockIdx.x * 32, k0 = blockIdx.y * 32;
    const int tx = threadIdx.x, ty = threadIdx.y;
    #pragma unroll
    for (int r = 0; r < 4; ++r) {
        const int k = k0 + ty + 8 * r, n = n0 + tx;
        t[ty + 8 * r][tx] = (k < K && n < N) ? W[(size_t)k * N + n] : 0.f;
    }
    __syncthreads();
    #pragma unroll
    for (int r = 0; r < 4; ++r) {
        const int k = k0 + tx, n = n0 + ty + 8 * r;
        if (k < Kp && n < Np) Wt[(size_t)n * Kp + k] = f2bf(t[tx][ty + 8 * r]);
    }
}

// three 1024x1024 transposes in one launch (blockIdx.z selects)
struct WP3 { const float *s0, *s1, *s2; unsigned short *d0, *d1, *d2; };
__global__ void transpose_pack3(WP3 p)
{
    __shared__ float t[32][33];
    const float* W = (blockIdx.z == 0) ? p.s0 : (blockIdx.z == 1) ? p.s1 : p.s2;
    unsigned short* Wt = (blockIdx.z == 0) ? p.d0 : (blockIdx.z == 1) ? p.d1 : p.d2;
    const int n0 = blockIdx.x * 32, k0 = blockIdx.y * 32;
    const int tx = threadIdx.x, ty = threadIdx.y;
    #pragma unroll
    for (int r = 0; r < 4; ++r)
        t[ty + 8 * r][tx] = W[(size_t)(k0 + ty + 8 * r) * 1024 + n0 + tx];
    __syncthreads();
    #pragma unroll
    for (int r = 0; r < 4; ++r)
        Wt[(size_t)(n0 + ty + 8 * r) * 1024 + k0 + tx] = f2bf(t[tx][ty + 8 * r]);
}

// ---- zero dcd pad cols (2492..2495 of each row) ----
__global__ void zero_dcd_pad(unsigned short* __restrict__ dcd)
{
    const int i = blockIdx.x * 256 + threadIdx.x;
    if (i < 8192 * 4) dcd[(size_t)(i >> 2) * 2496 + 2492 + (i & 3)] = 0;
}

extern "C" void kernel_launch(void* const* d_in, const int* in_sizes, int n_in,
                              void* d_out, int out_size, void* d_ws, size_t ws_size,
                              hipStream_t stream)
{
    const float* x     = (const float*)d_in[0];
    const float* m     = (const float*)d_in[1];
    const float* enc_W = (const float*)d_in[2];
    const float* enc_U = (const float*)d_in[3];
    const float* enc_b = (const float*)d_in[4];
    const float* dec_W = (const float*)d_in[5];
    const float* dec_Um= (const float*)d_in[6];
    const float* dec_b = (const float*)d_in[7];
    const float* W_map = (const float*)d_in[8];
    const float* b_map = (const float*)d_in[9];
    const float* W1    = (const float*)d_in[10];
    const float* b1    = (const float*)d_in[11];
    const float* W2    = (const float*)d_in[12];
    const float* b2    = (const float*)d_in[13];
    const float* W3    = (const float*)d_in[14];
    const float* b3    = (const float*)d_in[15];
    const float* W_out = (const float*)d_in[16];
    const float* b_out = (const float*)d_in[17];
    float* out = (float*)d_out;

    const int B = 8192, FE = 69, FD = 45;
    const int KMP = 2496;

    char* ws = (char*)d_ws;
    size_t off = 0;
    auto alloc = [&](size_t bytes) -> void* {
        void* p = ws + off; off = (off + bytes + 255) & ~(size_t)255; return p;
    };
    unsigned short* WtE = (unsigned short*)alloc((size_t)1536 * 448 * 2);
    unsigned short* WtD = (unsigned short*)alloc((size_t)1536 * 448 * 2);
    unsigned short* WtM = (unsigned short*)alloc((size_t)1024 * KMP * 2);
    unsigned short* Wt1 = (unsigned short*)alloc((size_t)1024 * 1024 * 2);
    unsigned short* Wt2 = (unsigned short*)alloc((size_t)1024 * 1024 * 2);
    unsigned short* Wt3 = (unsigned short*)alloc((size_t)1024 * 1024 * 2);
    unsigned short* WtO = (unsigned short*)alloc((size_t)256 * 1024 * 2);
    float* bIE = (float*)alloc(1536 * 4);
    float* bID = (float*)alloc(1536 * 4);
    unsigned short* dcd = (unsigned short*)alloc((size_t)B * KMP * 2);
    unsigned short* a1  = (unsigned short*)alloc((size_t)B * 1024 * 2);
    unsigned short* a2  = (unsigned short*)alloc((size_t)B * 1024 * 2);

    // ---- weight packing (Kp=448 both, kk-major lane-major frags) ----
    PackArgs pa{enc_W, enc_U, enc_b, WtE, bIE, FE, FE + 356, 448,
                dec_W, dec_Um, dec_b, WtD, bID, FD, FD + 356, 448};
    pack_lstm2<<<dim3((1536 * 448 + 255) / 256, 2), 256, 0, stream>>>(pa);
    const dim3 tb(32, 8);
    transpose_pack<<<dim3(1024 / 32, KMP / 32), tb, 0, stream>>>(
        W_map, 2492, 1024, WtM, KMP, 1024);
    WP3 p3{W1, W2, W3, Wt1, Wt2, Wt3};
    transpose_pack3<<<dim3(32, 32, 3), tb, 0, stream>>>(p3);
    transpose_pack<<<dim3(256 / 32, 1024 / 32), tb, 0, stream>>>(
        W_out, 1024, 168, WtO, 1024, 256);
    zero_dcd_pad<<<(8192 * 4 + 255) / 256, 256, 0, stream>>>(dcd);

    // ---- persistent LSTM: one plain launch, zero grid sync ----
    lstm_persist<<<256, 768, 0, stream>>>(x, m, WtE, WtD, bIE, bID, dcd);

    // ---- MLP head ----
    gemm_mfma<EPI_RELU, 1, 0><<<dim3(64, 8), 512, 0, stream>>>(
        dcd, WtM, b_map, a1, 1024, 1024, KMP);
    gemm_mfma<EPI_TANH, 1, 0><<<dim3(64, 8), 512, 0, stream>>>(
        a1, Wt1, b1, a2, 1024, 1024, 1024);
    gemm_mfma<EPI_TANH, 1, 0><<<dim3(64, 8), 512, 0, stream>>>(
        a2, Wt2, b2, a1, 1024, 1024, 1024);
    gemm_mfma<EPI_TANH, 1, 0><<<dim3(64, 8), 512, 0, stream>>>(
        a1, Wt3, b3, a2, 1024, 1024, 1024);
    gemm_mfma<EPI_NONE, 0, 1><<<dim3(64, 2), 512, 0, stream>>>(
        a2, WtO, b_out, out, 168, 168, 1024);
}